// Round 1
// baseline (439.490 us; speedup 1.0000x reference)
//
#include <hip/hip_runtime.h>
#include <hip/hip_bf16.h>

#define D 128
#define K1 384
#define H 256
#define O 128
#define BE 64
#define LDF (K1 + 8)   // 392 ushorts per feat row (pad to break bank stride)
#define LDH (H + 8)    // 264 ushorts per h row

typedef __attribute__((ext_vector_type(8))) short bf16x8;
typedef __attribute__((ext_vector_type(4))) float f32x4;

__device__ inline ushort f2b(float f) {
    union { float f; unsigned u; } v; v.f = f;
    unsigned u = v.u;
    unsigned r = (u + 0x7fffu + ((u >> 16) & 1u)) >> 16;   // RNE
    return (ushort)r;
}

// Pre-convert + transpose weights into bf16 workspace:
//  W1t[n][k] = bf16(W1[k][n])  (n<256, k<384)
//  W2t[o][k] = bf16(W2[k][o])  (o<128, k<256)
__global__ void prep_weights(const float* __restrict__ W1, const float* __restrict__ W2,
                             ushort* __restrict__ W1t, ushort* __restrict__ W2t) {
    int tid = blockIdx.x * blockDim.x + threadIdx.x;
    if (tid < 256 * 384) {
        int n = tid / 384, k = tid % 384;
        W1t[tid] = f2b(W1[k * 256 + n]);
    } else {
        int t2 = tid - 256 * 384;
        if (t2 < 128 * 256) {
            int o = t2 / 256, k = t2 % 256;
            W2t[t2] = f2b(W2[k * 128 + o]);
        }
    }
}

__global__ __launch_bounds__(256, 2)
void edge_mlp(const float* __restrict__ x, const float* __restrict__ ea,
              const int* __restrict__ eidx,
              const float* __restrict__ b1, const float* __restrict__ b2,
              const ushort* __restrict__ W1t, const ushort* __restrict__ W2t,
              float* __restrict__ out, int E) {
    __shared__ ushort sF[BE * LDF];        // 50176 B; reused as sH after phase 1
    ushort* sH = sF;

    const int tid = threadIdx.x;
    const int wave = tid >> 6;
    const int lane = tid & 63;
    const int row16 = lane & 15;           // A-row within 16 / D-col within 16
    const int kgrp = lane >> 4;            // K-group (8 elems each)
    const long e0 = (long)blockIdx.x * BE;

    // ---- build feat tile: [sender | receiver | edge_attr] -> bf16 LDS ----
    {
        int i = tid >> 2;                  // edge within tile (0..63)
        int p = tid & 3;                   // 32-col quarter (0..3)
        long e = e0 + i; if (e >= E) e = E - 1;
        int s = eidx[2 * e], r = eidx[2 * e + 1];
        const float* src0 = x + (long)s * D + p * 32;
        const float* src1 = x + (long)r * D + p * 32;
        const float* src2 = ea + e * D + p * 32;
        ushort* dst = sF + i * LDF + p * 32;
        #pragma unroll
        for (int j = 0; j < 8; ++j) {
            float4 v = ((const float4*)src0)[j];
            ushort4 u; u.x = f2b(v.x); u.y = f2b(v.y); u.z = f2b(v.z); u.w = f2b(v.w);
            *(ushort4*)(dst + 0 * D + j * 4) = u;
        }
        #pragma unroll
        for (int j = 0; j < 8; ++j) {
            float4 v = ((const float4*)src1)[j];
            ushort4 u; u.x = f2b(v.x); u.y = f2b(v.y); u.z = f2b(v.z); u.w = f2b(v.w);
            *(ushort4*)(dst + 1 * D + j * 4) = u;
        }
        #pragma unroll
        for (int j = 0; j < 8; ++j) {
            float4 v = ((const float4*)src2)[j];
            ushort4 u; u.x = f2b(v.x); u.y = f2b(v.y); u.z = f2b(v.z); u.w = f2b(v.w);
            *(ushort4*)(dst + 2 * D + j * 4) = u;
        }
    }
    __syncthreads();

    // ---- phase 1: h(64x256) = relu(feat @ W1 + b1); wave owns cols [wave*64, +64) ----
    f32x4 acc[4][4];
    #pragma unroll
    for (int a = 0; a < 4; ++a)
        #pragma unroll
        for (int b = 0; b < 4; ++b) acc[a][b] = (f32x4){0.f, 0.f, 0.f, 0.f};

    const int wcol = wave * 64;
    for (int k0 = 0; k0 < K1; k0 += 32) {
        bf16x8 a[4], b[4];
        #pragma unroll
        for (int fr = 0; fr < 4; ++fr)
            a[fr] = *(const bf16x8*)(sF + (fr * 16 + row16) * LDF + k0 + kgrp * 8);
        #pragma unroll
        for (int fc = 0; fc < 4; ++fc)
            b[fc] = *(const bf16x8*)(W1t + (wcol + fc * 16 + row16) * K1 + k0 + kgrp * 8);
        #pragma unroll
        for (int fr = 0; fr < 4; ++fr)
            #pragma unroll
            for (int fc = 0; fc < 4; ++fc)
                acc[fr][fc] = __builtin_amdgcn_mfma_f32_16x16x32_bf16(a[fr], b[fc], acc[fr][fc], 0, 0, 0);
    }
    __syncthreads();   // all sF reads done before aliasing as sH

    // bias + relu + h -> LDS (bf16)
    #pragma unroll
    for (int fc = 0; fc < 4; ++fc) {
        int col = wcol + fc * 16 + row16;
        float bv = b1[col];
        #pragma unroll
        for (int fr = 0; fr < 4; ++fr) {
            #pragma unroll
            for (int r = 0; r < 4; ++r) {
                int row = fr * 16 + kgrp * 4 + r;
                float v = fmaxf(acc[fr][fc][r] + bv, 0.f);
                sH[row * LDH + col] = f2b(v);
            }
        }
    }
    __syncthreads();

    // ---- phase 2: out(64x128) = h @ W2 + b2; wave owns cols [wave*32, +32) ----
    f32x4 acc2[4][2];
    #pragma unroll
    for (int a = 0; a < 4; ++a)
        #pragma unroll
        for (int b = 0; b < 2; ++b) acc2[a][b] = (f32x4){0.f, 0.f, 0.f, 0.f};

    const int wo = wave * 32;
    for (int k0 = 0; k0 < H; k0 += 32) {
        bf16x8 a[4], b[2];
        #pragma unroll
        for (int fr = 0; fr < 4; ++fr)
            a[fr] = *(const bf16x8*)(sH + (fr * 16 + row16) * LDH + k0 + kgrp * 8);
        #pragma unroll
        for (int fc = 0; fc < 2; ++fc)
            b[fc] = *(const bf16x8*)(W2t + (wo + fc * 16 + row16) * H + k0 + kgrp * 8);
        #pragma unroll
        for (int fr = 0; fr < 4; ++fr)
            #pragma unroll
            for (int fc = 0; fc < 2; ++fc)
                acc2[fr][fc] = __builtin_amdgcn_mfma_f32_16x16x32_bf16(a[fr], b[fc], acc2[fr][fc], 0, 0, 0);
    }

    #pragma unroll
    for (int fc = 0; fc < 2; ++fc) {
        int col = wo + fc * 16 + row16;
        float bv = b2[col];
        #pragma unroll
        for (int fr = 0; fr < 4; ++fr) {
            #pragma unroll
            for (int r = 0; r < 4; ++r) {
                long row = e0 + fr * 16 + kgrp * 4 + r;
                if (row < E) out[row * O + col] = acc2[fr][fc][r] + bv;
            }
        }
    }
}

extern "C" void kernel_launch(void* const* d_in, const int* in_sizes, int n_in,
                              void* d_out, int out_size, void* d_ws, size_t ws_size,
                              hipStream_t stream) {
    const float* x  = (const float*)d_in[0];
    const float* ea = (const float*)d_in[1];
    const float* W1 = (const float*)d_in[2];
    const float* b1 = (const float*)d_in[3];
    const float* W2 = (const float*)d_in[4];
    const float* b2 = (const float*)d_in[5];
    const int* eidx = (const int*)d_in[6];
    float* out = (float*)d_out;

    const int E = in_sizes[1] / D;          // 500000
    ushort* W1t = (ushort*)d_ws;            // 256*384 ushorts
    ushort* W2t = W1t + 256 * 384;          // 128*256 ushorts (total 256 KiB)

    prep_weights<<<512, 256, 0, stream>>>(W1, W2, W1t, W2t);

    int nb = (E + BE - 1) / BE;
    edge_mlp<<<nb, 256, 0, stream>>>(x, ea, eidx, b1, b2, W1t, W2t, out, E);
}

// Round 2
// 397.556 us; speedup vs baseline: 1.1055x; 1.1055x over previous
//
#include <hip/hip_runtime.h>
#include <hip/hip_bf16.h>

#define D 128
#define K1 384
#define H 256
#define O 128
#define BE 64
#define LDEA 136       // ea tile leading dim (ushorts)
#define LDH 264        // h tile leading dim (ushorts)
#define LDF (K1 + 8)   // fallback path feat leading dim
#define LDHF (H + 8)

typedef __attribute__((ext_vector_type(8))) short bf16x8;
typedef __attribute__((ext_vector_type(4))) float f32x4;

__device__ inline ushort f2b(float f) {
    union { float f; unsigned u; } v; v.f = f;
    unsigned u = v.u;
    unsigned r = (u + 0x7fffu + ((u >> 16) & 1u)) >> 16;   // RNE
    return (ushort)r;
}
__device__ inline float b2f(ushort u) {
    union { unsigned u; float f; } v; v.u = ((unsigned)u) << 16; return v.f;
}

// W1t[n][k] = bf16(W1[k][n])  (n<256, k<384) ; W2t[o][k] = bf16(W2[k][o])
__global__ void prep_weights(const float* __restrict__ W1, const float* __restrict__ W2,
                             ushort* __restrict__ W1t, ushort* __restrict__ W2t) {
    int tid = blockIdx.x * blockDim.x + threadIdx.x;
    if (tid < 256 * 384) {
        int n = tid / 384, k = tid % 384;
        W1t[tid] = f2b(W1[k * 256 + n]);
    } else {
        int t2 = tid - 256 * 384;
        if (t2 < 128 * 256) {
            int o = t2 / 256, k = t2 % 256;
            W2t[t2] = f2b(W2[k * 128 + o]);
        }
    }
}

// Per-node projections, permuted layout:
//  XA[n][row16*16 + wv*4 + fc] = bf16( (x[n] @ W1[0:128])[col] + b1[col] ),  col = wv*64+fc*16+row16
//  XB[n][same p]               = bf16( (x[n] @ W1[128:256])[col] )
__global__ __launch_bounds__(256, 2)
void node_proj(const float* __restrict__ x, const float* __restrict__ b1,
               const ushort* __restrict__ W1t,
               ushort* __restrict__ XA, ushort* __restrict__ XB, int N) {
    __shared__ ushort sX[64 * LDEA];
    const int tid = threadIdx.x, wave = tid >> 6, lane = tid & 63;
    const int row16 = lane & 15, kgrp = lane >> 4;
    const long n0 = (long)blockIdx.x * 64;

    {   // stage x tile (64 nodes x 128) as bf16
        int i = tid >> 2, p = tid & 3;
        long n = n0 + i; if (n >= N) n = N - 1;
        const float* src = x + n * D + p * 32;
        ushort* dst = sX + i * LDEA + p * 32;
        #pragma unroll
        for (int j = 0; j < 8; ++j) {
            float4 v = ((const float4*)src)[j];
            ushort4 u; u.x = f2b(v.x); u.y = f2b(v.y); u.z = f2b(v.z); u.w = f2b(v.w);
            *(ushort4*)(dst + j * 4) = u;
        }
    }
    __syncthreads();

    f32x4 accA[4][4], accB[4][4];
    #pragma unroll
    for (int a = 0; a < 4; ++a)
        #pragma unroll
        for (int b = 0; b < 4; ++b) { accA[a][b] = (f32x4){0,0,0,0}; accB[a][b] = (f32x4){0,0,0,0}; }

    const int wcol = wave * 64;
    #pragma unroll
    for (int ks = 0; ks < 4; ++ks) {
        int k0 = ks * 32;
        bf16x8 a[4], bA[4], bB[4];
        #pragma unroll
        for (int fr = 0; fr < 4; ++fr)
            a[fr] = *(const bf16x8*)(sX + (fr * 16 + row16) * LDEA + k0 + kgrp * 8);
        #pragma unroll
        for (int fc = 0; fc < 4; ++fc) {
            const ushort* wb = W1t + (wcol + fc * 16 + row16) * K1 + k0 + kgrp * 8;
            bA[fc] = *(const bf16x8*)(wb);
            bB[fc] = *(const bf16x8*)(wb + 128);
        }
        #pragma unroll
        for (int fr = 0; fr < 4; ++fr)
            #pragma unroll
            for (int fc = 0; fc < 4; ++fc) {
                accA[fr][fc] = __builtin_amdgcn_mfma_f32_16x16x32_bf16(a[fr], bA[fc], accA[fr][fc], 0, 0, 0);
                accB[fr][fc] = __builtin_amdgcn_mfma_f32_16x16x32_bf16(a[fr], bB[fc], accB[fr][fc], 0, 0, 0);
            }
    }

    float bv[4];
    #pragma unroll
    for (int fc = 0; fc < 4; ++fc) bv[fc] = b1[wcol + fc * 16 + row16];

    #pragma unroll
    for (int fr = 0; fr < 4; ++fr)
        #pragma unroll
        for (int r = 0; r < 4; ++r) {
            long n = n0 + fr * 16 + kgrp * 4 + r;
            if (n < N) {
                ushort4 ua, ub;
                ua.x = f2b(accA[fr][0][r] + bv[0]); ua.y = f2b(accA[fr][1][r] + bv[1]);
                ua.z = f2b(accA[fr][2][r] + bv[2]); ua.w = f2b(accA[fr][3][r] + bv[3]);
                ub.x = f2b(accB[fr][0][r]); ub.y = f2b(accB[fr][1][r]);
                ub.z = f2b(accB[fr][2][r]); ub.w = f2b(accB[fr][3][r]);
                long p = n * 256 + row16 * 16 + wave * 4;
                *(ushort4*)(XA + p) = ua;
                *(ushort4*)(XB + p) = ub;
            }
        }
}

__global__ __launch_bounds__(256, 4)
void edge_mlp2(const float* __restrict__ ea, const int* __restrict__ eidx,
               const ushort* __restrict__ XA, const ushort* __restrict__ XB,
               const ushort* __restrict__ W1t, const ushort* __restrict__ W2t,
               const float* __restrict__ b2, float* __restrict__ out, int E) {
    __shared__ ushort sBuf[64 * LDH];      // 33792 B; sEA region aliased, then sH
    ushort* sEA = sBuf;
    ushort* sH  = sBuf;

    const int tid = threadIdx.x, wave = tid >> 6, lane = tid & 63;
    const int row16 = lane & 15, kgrp = lane >> 4;
    const long e0 = (long)blockIdx.x * BE;

    // ---- gather per-edge node projections (issue loads early) ----
    ushort4 ga[4][4], gb[4][4];
    const int poff = row16 * 16 + wave * 4;
    #pragma unroll
    for (int fr = 0; fr < 4; ++fr)
        #pragma unroll
        for (int r = 0; r < 4; ++r) {
            long e = e0 + fr * 16 + kgrp * 4 + r; if (e >= E) e = E - 1;
            int2 sr = *(const int2*)(eidx + 2 * e);
            ga[fr][r] = *(const ushort4*)(XA + (long)sr.x * 256 + poff);
            gb[fr][r] = *(const ushort4*)(XB + (long)sr.y * 256 + poff);
        }

    // ---- stage ea tile as bf16 ----
    {
        int i = tid >> 2, p = tid & 3;
        long e = e0 + i; if (e >= E) e = E - 1;
        const float* src = ea + e * D + p * 32;
        ushort* dst = sEA + i * LDEA + p * 32;
        #pragma unroll
        for (int j = 0; j < 8; ++j) {
            float4 v = ((const float4*)src)[j];
            ushort4 u; u.x = f2b(v.x); u.y = f2b(v.y); u.z = f2b(v.z); u.w = f2b(v.w);
            *(ushort4*)(dst + j * 4) = u;
        }
    }

    // ---- init acc from gathers (gather regs die here) ----
    f32x4 acc[4][4];
    #pragma unroll
    for (int fr = 0; fr < 4; ++fr)
        #pragma unroll
        for (int r = 0; r < 4; ++r) {
            const ushort* pa = (const ushort*)&ga[fr][r];
            const ushort* pb = (const ushort*)&gb[fr][r];
            #pragma unroll
            for (int fc = 0; fc < 4; ++fc)
                acc[fr][fc][r] = b2f(pa[fc]) + b2f(pb[fc]);
        }
    __syncthreads();

    // ---- phase 1: acc += ea @ W1c   (K=128, W1c = W1t rows k 256..384) ----
    const int wcol = wave * 64;
    #pragma unroll
    for (int ks = 0; ks < 4; ++ks) {
        int k0 = ks * 32;
        bf16x8 a[4], b[4];
        #pragma unroll
        for (int fr = 0; fr < 4; ++fr)
            a[fr] = *(const bf16x8*)(sEA + (fr * 16 + row16) * LDEA + k0 + kgrp * 8);
        #pragma unroll
        for (int fc = 0; fc < 4; ++fc)
            b[fc] = *(const bf16x8*)(W1t + (wcol + fc * 16 + row16) * K1 + 256 + k0 + kgrp * 8);
        #pragma unroll
        for (int fr = 0; fr < 4; ++fr)
            #pragma unroll
            for (int fc = 0; fc < 4; ++fc)
                acc[fr][fc] = __builtin_amdgcn_mfma_f32_16x16x32_bf16(a[fr], b[fc], acc[fr][fc], 0, 0, 0);
    }
    __syncthreads();   // all sEA reads done before aliasing as sH

    // ---- relu + h -> LDS (bf16) ----
    #pragma unroll
    for (int fr = 0; fr < 4; ++fr)
        #pragma unroll
        for (int r = 0; r < 4; ++r) {
            int row = fr * 16 + kgrp * 4 + r;
            #pragma unroll
            for (int fc = 0; fc < 4; ++fc) {
                float v = fmaxf(acc[fr][fc][r], 0.f);
                sH[row * LDH + wcol + fc * 16 + row16] = f2b(v);
            }
        }
    __syncthreads();

    // ---- phase 2: out = h @ W2 + b2 ----
    f32x4 acc2[4][2];
    #pragma unroll
    for (int a = 0; a < 4; ++a)
        #pragma unroll
        for (int b = 0; b < 2; ++b) acc2[a][b] = (f32x4){0,0,0,0};

    const int wo = wave * 32;
    #pragma unroll
    for (int ks = 0; ks < 8; ++ks) {
        int k0 = ks * 32;
        bf16x8 a[4], b[2];
        #pragma unroll
        for (int fr = 0; fr < 4; ++fr)
            a[fr] = *(const bf16x8*)(sH + (fr * 16 + row16) * LDH + k0 + kgrp * 8);
        #pragma unroll
        for (int fc = 0; fc < 2; ++fc)
            b[fc] = *(const bf16x8*)(W2t + (wo + fc * 16 + row16) * H + k0 + kgrp * 8);
        #pragma unroll
        for (int fr = 0; fr < 4; ++fr)
            #pragma unroll
            for (int fc = 0; fc < 2; ++fc)
                acc2[fr][fc] = __builtin_amdgcn_mfma_f32_16x16x32_bf16(a[fr], b[fc], acc2[fr][fc], 0, 0, 0);
    }

    #pragma unroll
    for (int fc = 0; fc < 2; ++fc) {
        int col = wo + fc * 16 + row16;
        float bv = b2[col];
        #pragma unroll
        for (int fr = 0; fr < 4; ++fr)
            #pragma unroll
            for (int r = 0; r < 4; ++r) {
                long row = e0 + fr * 16 + kgrp * 4 + r;
                if (row < E) out[row * O + col] = acc2[fr][fc][r] + bv;
            }
    }
}

// ---------------- fallback (round-1) kernel: used only if ws too small ----------------
__global__ __launch_bounds__(256, 2)
void edge_mlp(const float* __restrict__ x, const float* __restrict__ ea,
              const int* __restrict__ eidx,
              const float* __restrict__ b1, const float* __restrict__ b2,
              const ushort* __restrict__ W1t, const ushort* __restrict__ W2t,
              float* __restrict__ out, int E) {
    __shared__ ushort sF[BE * LDF];
    ushort* sH = sF;
    const int tid = threadIdx.x, wave = tid >> 6, lane = tid & 63;
    const int row16 = lane & 15, kgrp = lane >> 4;
    const long e0 = (long)blockIdx.x * BE;
    {
        int i = tid >> 2, p = tid & 3;
        long e = e0 + i; if (e >= E) e = E - 1;
        int s = eidx[2 * e], r = eidx[2 * e + 1];
        const float* src0 = x + (long)s * D + p * 32;
        const float* src1 = x + (long)r * D + p * 32;
        const float* src2 = ea + e * D + p * 32;
        ushort* dst = sF + i * LDF + p * 32;
        #pragma unroll
        for (int j = 0; j < 8; ++j) {
            float4 v = ((const float4*)src0)[j];
            ushort4 u; u.x = f2b(v.x); u.y = f2b(v.y); u.z = f2b(v.z); u.w = f2b(v.w);
            *(ushort4*)(dst + 0 * D + j * 4) = u;
        }
        #pragma unroll
        for (int j = 0; j < 8; ++j) {
            float4 v = ((const float4*)src1)[j];
            ushort4 u; u.x = f2b(v.x); u.y = f2b(v.y); u.z = f2b(v.z); u.w = f2b(v.w);
            *(ushort4*)(dst + 1 * D + j * 4) = u;
        }
        #pragma unroll
        for (int j = 0; j < 8; ++j) {
            float4 v = ((const float4*)src2)[j];
            ushort4 u; u.x = f2b(v.x); u.y = f2b(v.y); u.z = f2b(v.z); u.w = f2b(v.w);
            *(ushort4*)(dst + 2 * D + j * 4) = u;
        }
    }
    __syncthreads();
    f32x4 acc[4][4];
    #pragma unroll
    for (int a = 0; a < 4; ++a)
        #pragma unroll
        for (int b = 0; b < 4; ++b) acc[a][b] = (f32x4){0,0,0,0};
    const int wcol = wave * 64;
    for (int k0 = 0; k0 < K1; k0 += 32) {
        bf16x8 a[4], b[4];
        #pragma unroll
        for (int fr = 0; fr < 4; ++fr)
            a[fr] = *(const bf16x8*)(sF + (fr * 16 + row16) * LDF + k0 + kgrp * 8);
        #pragma unroll
        for (int fc = 0; fc < 4; ++fc)
            b[fc] = *(const bf16x8*)(W1t + (wcol + fc * 16 + row16) * K1 + k0 + kgrp * 8);
        #pragma unroll
        for (int fr = 0; fr < 4; ++fr)
            #pragma unroll
            for (int fc = 0; fc < 4; ++fc)
                acc[fr][fc] = __builtin_amdgcn_mfma_f32_16x16x32_bf16(a[fr], b[fc], acc[fr][fc], 0, 0, 0);
    }
    __syncthreads();
    #pragma unroll
    for (int fc = 0; fc < 4; ++fc) {
        int col = wcol + fc * 16 + row16;
        float bv = b1[col];
        #pragma unroll
        for (int fr = 0; fr < 4; ++fr)
            #pragma unroll
            for (int r = 0; r < 4; ++r) {
                int row = fr * 16 + kgrp * 4 + r;
                float v = fmaxf(acc[fr][fc][r] + bv, 0.f);
                sH[row * LDHF + col] = f2b(v);
            }
    }
    __syncthreads();
    f32x4 acc2[4][2];
    #pragma unroll
    for (int a = 0; a < 4; ++a)
        #pragma unroll
        for (int b = 0; b < 2; ++b) acc2[a][b] = (f32x4){0,0,0,0};
    const int wo = wave * 32;
    for (int k0 = 0; k0 < H; k0 += 32) {
        bf16x8 a[4], b[2];
        #pragma unroll
        for (int fr = 0; fr < 4; ++fr)
            a[fr] = *(const bf16x8*)(sH + (fr * 16 + row16) * LDHF + k0 + kgrp * 8);
        #pragma unroll
        for (int fc = 0; fc < 2; ++fc)
            b[fc] = *(const bf16x8*)(W2t + (wo + fc * 16 + row16) * H + k0 + kgrp * 8);
        #pragma unroll
        for (int fr = 0; fr < 4; ++fr)
            #pragma unroll
            for (int fc = 0; fc < 2; ++fc)
                acc2[fr][fc] = __builtin_amdgcn_mfma_f32_16x16x32_bf16(a[fr], b[fc], acc2[fr][fc], 0, 0, 0);
    }
    #pragma unroll
    for (int fc = 0; fc < 2; ++fc) {
        int col = wo + fc * 16 + row16;
        float bv = b2[col];
        #pragma unroll
        for (int fr = 0; fr < 4; ++fr)
            #pragma unroll
            for (int r = 0; r < 4; ++r) {
                long row = e0 + fr * 16 + kgrp * 4 + r;
                if (row < E) out[row * O + col] = acc2[fr][fc][r] + bv;
            }
    }
}

extern "C" void kernel_launch(void* const* d_in, const int* in_sizes, int n_in,
                              void* d_out, int out_size, void* d_ws, size_t ws_size,
                              hipStream_t stream) {
    const float* x  = (const float*)d_in[0];
    const float* ea = (const float*)d_in[1];
    const float* W1 = (const float*)d_in[2];
    const float* b1 = (const float*)d_in[3];
    const float* W2 = (const float*)d_in[4];
    const float* b2 = (const float*)d_in[5];
    const int* eidx = (const int*)d_in[6];
    float* out = (float*)d_out;

    const int E = in_sizes[1] / D;          // 500000
    const int N = in_sizes[0] / D;          // 50000

    ushort* W1t = (ushort*)d_ws;                    // 256*384
    ushort* W2t = W1t + 256 * 384;                  // 128*256
    ushort* XA  = W2t + 128 * 256;                  // N*256
    ushort* XB  = XA + (size_t)N * 256;             // N*256
    size_t need = (size_t)(256 * 384 + 128 * 256) * 2 + (size_t)N * 256 * 2 * 2;

    prep_weights<<<512, 256, 0, stream>>>(W1, W2, W1t, W2t);

    int nb = (E + BE - 1) / BE;
    if (ws_size >= need) {
        int nbn = (N + 63) / 64;
        node_proj<<<nbn, 256, 0, stream>>>(x, b1, W1t, XA, XB, N);
        edge_mlp2<<<nb, 256, 0, stream>>>(ea, eidx, XA, XB, W1t, W2t, b2, out, E);
    } else {
        edge_mlp<<<nb, 256, 0, stream>>>(x, ea, eidx, b1, b2, W1t, W2t, out, E);
    }
}